// Round 9
// baseline (475.985 us; speedup 1.0000x reference)
//
#include <hip/hip_runtime.h>

// Monarch block-MLP, round 9: break the barrier vmcnt-drain.
// All rounds 3-8 sat at MfmaUtil 2-3% because __syncthreads() compiles to
// s_waitcnt vmcnt(0) -- every prefetch drained at each phase boundary.
// R9: lgkm-only barriers (raw s_barrier + lgkmcnt(0)), weights/x loaded into
// named register arrays one full phase ahead, consumed via compiler-counted
// vmcnt(N>0). R8's stile-sweep geometry (x read once in K1), direct stores.

typedef __attribute__((ext_vector_type(8))) short short8;
typedef __attribute__((ext_vector_type(4))) float floatx4;
typedef unsigned int uint;

#define MFMA32(a, b, c) __builtin_amdgcn_mfma_f32_16x16x32_bf16(a, b, c, 0, 0, 0)

__device__ __forceinline__ unsigned short f2bf(float f) {
    uint u = __float_as_uint(f);
    uint r = 0x7FFFu + ((u >> 16) & 1u);
    return (unsigned short)((u + r) >> 16);
}
__device__ __forceinline__ short8 ld8(const unsigned short* p) {
    return *reinterpret_cast<const short8*>(p);
}

// LDS-ordering barrier that does NOT drain vmcnt (keeps global prefetches
// in flight across the barrier -- the whole point of this round).
__device__ __forceinline__ void lgkm_barrier() {
    __builtin_amdgcn_sched_barrier(0);
    asm volatile("s_waitcnt lgkmcnt(0)" ::: "memory");
    __builtin_amdgcn_s_barrier();
    __builtin_amdgcn_sched_barrier(0);
}

// out[b][c][r] = bf16(in[b][r][c])
__global__ void transpose_cast_k(const float* __restrict__ in,
                                 unsigned short* __restrict__ out,
                                 int Bn, int R, int C) {
    int total = Bn * R * C;
    int stride = gridDim.x * blockDim.x;
    for (int idx = blockIdx.x * blockDim.x + threadIdx.x; idx < total; idx += stride) {
        int rc = R * C;
        int b = idx / rc;
        int rem = idx - b * rc;
        int c = rem / R;
        int r = rem - c * R;
        out[idx] = f2bf(in[(size_t)(b * R + r) * C + c]);
    }
}

// MFMA 16x16x32 bf16 layouts (m89-verified):
//   A: row = lane&15, k = (lane>>4)*8 + i ;  B: col = lane&15, same k
//   D: col = lane&15, row = (lane>>4)*4 + reg
template<int KB, int SN, bool ELU, bool F32IN>
__global__ __launch_bounds__(512, 2) void fusedR9(
    const void* __restrict__ xin,             // [bs][KB*64] f32 or bf16
    const unsigned short* __restrict__ wat,   // [KB][SN][64] bf16
    const unsigned short* __restrict__ wbt,   // [SN][64][KB] bf16
    const float* __restrict__ bias,           // [SN*64]
    unsigned short* __restrict__ ob,          // bf16 out (ELU)
    float* __restrict__ of)                   // f32 out
{
    constexpr int G  = KB / 64;       // 64-kb groups (1 or 2)
    constexpr int NS = SN / 16;       // stiles (8 or 4)
    constexpr int IW = KB * 64;
    constexpr int OW = SN * 64;

    const int tid  = threadIdx.x;
    const int lane = tid & 63;
    const int wv   = tid >> 6;        // 0..7
    const int l15  = lane & 15;
    const int l4   = lane >> 4;       // 0..3
    const int r0   = blockIdx.x * 16;

    // y0[r16][s(17)][k(72)] bf16 = 39168 B, XOR-swizzled (byte ^ (r&7)<<4).
    __shared__ __align__(16) unsigned short y0s[16 * 17 * 72];
    char* yb = (char*)y0s;
    auto yoff = [&](int r, int s, int k) -> int {
        return (((r * 17 + s) * 72 + k) * 2) ^ ((r & 7) << 4);
    };

    short8 xf[16];   // wave's x A-frags for current 64-kb group (64 VGPR)
    short8 wa[16];   // stage-A weights, current phase       (64 VGPR)
    short8 wb[16];   // stage-B weights, current phase       (64 VGPR)

    auto loadX = [&](int g) {
        if constexpr (F32IN) {
            const float* xr = (const float*)xin + (size_t)(r0 + l15) * IW;
#pragma unroll
            for (int t = 0; t < 8; ++t) {
                const float* p = xr + (g * 64 + wv * 8 + t) * 64 + l4 * 8;
                floatx4 u0 = *reinterpret_cast<const floatx4*>(p);
                floatx4 u1 = *reinterpret_cast<const floatx4*>(p + 4);
                floatx4 u2 = *reinterpret_cast<const floatx4*>(p + 32);
                floatx4 u3 = *reinterpret_cast<const floatx4*>(p + 36);
                short8 a, b;
#pragma unroll
                for (int i = 0; i < 4; ++i) {
                    a[i] = (short)f2bf(u0[i]);  a[i + 4] = (short)f2bf(u1[i]);
                    b[i] = (short)f2bf(u2[i]);  b[i + 4] = (short)f2bf(u3[i]);
                }
                xf[t * 2] = a;  xf[t * 2 + 1] = b;
            }
        } else {
            const unsigned short* xr =
                (const unsigned short*)xin + (size_t)(r0 + l15) * IW;
#pragma unroll
            for (int t = 0; t < 8; ++t) {
                const unsigned short* p = xr + (g * 64 + wv * 8 + t) * 64 + l4 * 8;
                xf[t * 2]     = ld8(p);
                xf[t * 2 + 1] = ld8(p + 32);
            }
        }
    };
    auto loadWA = [&](int ss, int g) {
#pragma unroll
        for (int t = 0; t < 8; ++t) {
            const unsigned short* p =
                wat + ((size_t)(g * 64 + wv * 8 + t) * SN + ss * 16 + l15) * 64 + l4 * 8;
            wa[t * 2]     = ld8(p);
            wa[t * 2 + 1] = ld8(p + 32);
        }
    };
    auto loadWB = [&](int ss, int g) {
#pragma unroll
        for (int sl = 0; sl < 2; ++sl)
#pragma unroll
            for (int jq = 0; jq < 4; ++jq) {
                const unsigned short* p =
                    wbt + ((size_t)(ss * 16 + wv * 2 + sl) * 64 + jq * 16 + l15) * KB
                        + g * 64 + l4 * 8;
                wb[(sl * 4 + jq) * 2]     = ld8(p);
                wb[(sl * 4 + jq) * 2 + 1] = ld8(p + 32);
            }
    };

    loadX(0);
    loadWA(0, 0);

    for (int ss = 0; ss < NS; ++ss) {
        floatx4 acc[2][4];
#pragma unroll
        for (int sl = 0; sl < 2; ++sl)
#pragma unroll
            for (int jq = 0; jq < 4; ++jq) acc[sl][jq] = (floatx4){0.f, 0.f, 0.f, 0.f};

        for (int g = 0; g < G; ++g) {
            loadWB(ss, g);            // in flight across stage A

            // ---- stage A: 16 MFMA from registers, packed y0 writes ----
#pragma unroll
            for (int tp = 0; tp < 4; ++tp) {
                const int t0 = tp * 2, t1 = t0 + 1;
                floatx4 d0 = (floatx4){0.f, 0.f, 0.f, 0.f};
                floatx4 d1 = (floatx4){0.f, 0.f, 0.f, 0.f};
                d0 = MFMA32(xf[2 * t0],     wa[2 * t0],     d0);
                d0 = MFMA32(xf[2 * t0 + 1], wa[2 * t0 + 1], d0);
                d1 = MFMA32(xf[2 * t1],     wa[2 * t1],     d1);
                d1 = MFMA32(xf[2 * t1 + 1], wa[2 * t1 + 1], d1);
#pragma unroll
                for (int rg = 0; rg < 4; ++rg) {
                    uint pk = (uint)f2bf(d0[rg]) | ((uint)f2bf(d1[rg]) << 16);
                    *reinterpret_cast<uint*>(
                        yb + yoff(l4 * 4 + rg, l15, wv * 8 + t0)) = pk;
                }
            }

            // ---- prefetch next phase (wa consumed, safe to refill) ----
            const bool last = (ss == NS - 1) && (g == G - 1);
            if (!last) {
                const int nss = (g + 1 < G) ? ss : ss + 1;
                const int ng  = (g + 1 < G) ? g + 1 : 0;
                loadWA(nss, ng);
                if (G > 1) loadX(ng);
            }

            lgkm_barrier();           // y0 visible; vmcnt untouched

            // ---- stage B: 4 ds_read_b128 + 16 MFMA (wb via counted vmcnt) ----
#pragma unroll
            for (int sl = 0; sl < 2; ++sl) {
                const int s_local = wv * 2 + sl;
                short8 af0 = *reinterpret_cast<const short8*>(
                    yb + yoff(l15, s_local, l4 * 8));
                short8 af1 = *reinterpret_cast<const short8*>(
                    yb + yoff(l15, s_local, 32 + l4 * 8));
#pragma unroll
                for (int jq = 0; jq < 4; ++jq) {
                    acc[sl][jq] = MFMA32(af0, wb[(sl * 4 + jq) * 2],     acc[sl][jq]);
                    acc[sl][jq] = MFMA32(af1, wb[(sl * 4 + jq) * 2 + 1], acc[sl][jq]);
                }
            }

            lgkm_barrier();           // y0 consumed; next stage A may overwrite
        }

        // ---- epilogue: bias (+ELU), direct stores from acc ----
#pragma unroll
        for (int sl = 0; sl < 2; ++sl) {
            const int sg = ss * 16 + wv * 2 + sl;
#pragma unroll
            for (int jq = 0; jq < 4; ++jq) {
                const float bv = bias[sg * 64 + jq * 16 + l15];
#pragma unroll
                for (int rg = 0; rg < 4; ++rg) {
                    float v = acc[sl][jq][rg] + bv;
                    const size_t idx =
                        (size_t)(r0 + l4 * 4 + rg) * OW + sg * 64 + jq * 16 + l15;
                    if constexpr (ELU) {
                        v = v > 0.f ? v : (__expf(v) - 1.f);
                        ob[idx] = f2bf(v);
                    } else {
                        of[idx] = v;
                    }
                }
            }
        }
    }
}

extern "C" void kernel_launch(void* const* d_in, const int* in_sizes, int n_in,
                              void* d_out, int out_size, void* d_ws, size_t ws_size,
                              hipStream_t stream) {
    const float* x  = (const float*)d_in[0];
    const float* w0 = (const float*)d_in[1];
    const float* w1 = (const float*)d_in[2];
    const float* b1 = (const float*)d_in[3];
    const float* w2 = (const float*)d_in[4];
    const float* w3 = (const float*)d_in[5];
    const float* b3 = (const float*)d_in[6];
    float* out = (float*)d_out;

    const int bs = in_sizes[0] / 4096;

    // ws (u16): z[bs*8192] | w0t | w1t | w2t | w3t
    unsigned short* z   = (unsigned short*)d_ws;
    const size_t zElems = (size_t)bs * 8192;
    unsigned short* w0t = z + zElems;
    unsigned short* w1t = w0t + 64 * 128 * 64;
    unsigned short* w2t = w1t + 128 * 64 * 64;
    unsigned short* w3t = w2t + 128 * 64 * 64;
    const size_t need = (zElems + 4ull * 524288) * sizeof(unsigned short);
    if (n_in < 7 || (bs & 15) || ws_size < need) return;

    transpose_cast_k<<<dim3(512), dim3(256), 0, stream>>>(w0, w0t, 64, 64, 128);
    transpose_cast_k<<<dim3(512), dim3(256), 0, stream>>>(w1, w1t, 128, 64, 64);
    transpose_cast_k<<<dim3(512), dim3(256), 0, stream>>>(w2, w2t, 128, 64, 64);
    transpose_cast_k<<<dim3(512), dim3(256), 0, stream>>>(w3, w3t, 64, 128, 64);

    // K1: x (f32) -> z (bf16, +b1, ELU); x read once per wg (reg-resident)
    fusedR9<64, 128, true, true><<<dim3(bs / 16), dim3(512), 0, stream>>>(
        x, w0t, w1t, b1, z, nullptr);
    // K2: z (bf16) -> out (f32, +b3)
    fusedR9<128, 64, false, false><<<dim3(bs / 16), dim3(512), 0, stream>>>(
        z, w2t, w3t, b3, nullptr, out);
}

// Round 10
// 321.335 us; speedup vs baseline: 1.4813x; 1.4813x over previous
//
#include <hip/hip_runtime.h>

// Monarch block-MLP, round 10.
// K1 (fused 0_0+0_1, x reg-resident) kept from R9 (+staged z-write).
// K2 replaced by two clean block-diagonal GEMM passes:
//   P3 (stage 1_0): block-diag in n -> z read ONCE; weights (128KB, swizzled)
//       in LDS, B-frags hoisted to regs once; y2 stored TRANSPOSED
//       [b][nsl8][j64][nl16] via LDS staging; y2t aliases z (safe: each wg
//       overwrites exactly the chunk it read, barrier-ordered).
//   P4 (stage 1_1): block-diag in out-s -> y2t read ONCE; weights in LDS,
//       B-frags in regs; main loop = 4 A-loads + 16 MFMA, no barriers.
// Slice = blockIdx&7 -> XCD-pinned weight slices (L2-hot).

typedef __attribute__((ext_vector_type(8))) short short8;
typedef __attribute__((ext_vector_type(4))) float floatx4;
typedef unsigned int uint;
typedef unsigned short ushort;

#define MFMA32(a, b, c) __builtin_amdgcn_mfma_f32_16x16x32_bf16(a, b, c, 0, 0, 0)

__device__ __forceinline__ ushort f2bf(float f) {
    uint u = __float_as_uint(f);
    uint r = 0x7FFFu + ((u >> 16) & 1u);
    return (ushort)((u + r) >> 16);
}
__device__ __forceinline__ short8 ld8(const ushort* p) {
    return *reinterpret_cast<const short8*>(p);
}
__device__ __forceinline__ void gload_lds16(const void* g, void* l) {
    __builtin_amdgcn_global_load_lds(
        (const __attribute__((address_space(1))) unsigned int*)g,
        (__attribute__((address_space(3))) unsigned int*)l, 16, 0, 0);
}
__device__ __forceinline__ void lgkm_barrier() {
    __builtin_amdgcn_sched_barrier(0);
    asm volatile("s_waitcnt lgkmcnt(0)" ::: "memory");
    __builtin_amdgcn_s_barrier();
    __builtin_amdgcn_sched_barrier(0);
}

// out[b][c][r] = bf16(in[b][r][c])
__global__ void transpose_cast_k(const float* __restrict__ in,
                                 ushort* __restrict__ out,
                                 int Bn, int R, int C) {
    int total = Bn * R * C;
    int stride = gridDim.x * blockDim.x;
    for (int idx = blockIdx.x * blockDim.x + threadIdx.x; idx < total; idx += stride) {
        int rc = R * C;
        int b = idx / rc;
        int rem = idx - b * rc;
        int c = rem / R;
        int r = rem - c * R;
        out[idx] = f2bf(in[(size_t)(b * R + r) * C + c]);
    }
}

// Transposed + XOR-swizzled: block b, elem (c,r) at byte ((c*R+r)*2)^((c&7)<<4)
__global__ void transpose_cast_swz(const float* __restrict__ in,
                                   ushort* __restrict__ out,
                                   int Bn, int R, int C) {
    int total = Bn * R * C;
    int stride = gridDim.x * blockDim.x;
    for (int idx = blockIdx.x * blockDim.x + threadIdx.x; idx < total; idx += stride) {
        int rc = R * C;
        int b = idx / rc;
        int rem = idx - b * rc;
        int c = rem / R;
        int r = rem - c * R;
        int byteoff = ((c * R + r) * 2) ^ ((c & 7) << 4);
        *reinterpret_cast<ushort*>((char*)out + (size_t)b * rc * 2 + byteoff) =
            f2bf(in[(size_t)(b * R + r) * C + c]);
    }
}

// ---- K1: fused stage 0_0 + 0_1 (x f32 -> z bf16, +b1, ELU) ----
// MFMA 16x16x32 bf16 layouts (m89-verified):
//   A: row=lane&15, k=(lane>>4)*8+i ; B: col=lane&15, same k
//   D: col=lane&15, row=(lane>>4)*4+reg
__global__ __launch_bounds__(512, 2) void fusedK1(
    const float* __restrict__ xf,             // [bs][4096] f32
    const ushort* __restrict__ wat,           // [64 kb][128 s][64 m]
    const ushort* __restrict__ wbt,           // [128 s][64 j][64 k]
    const float* __restrict__ bias,           // [8192]
    ushort* __restrict__ ob)                  // z bf16 [bs][8192]
{
    constexpr int NS = 8;
    const int tid  = threadIdx.x;
    const int lane = tid & 63;
    const int wv   = tid >> 6;
    const int l15  = lane & 15;
    const int l4   = lane >> 4;
    const int r0   = blockIdx.x * 16;

    __shared__ __align__(16) ushort y0s[16 * 17 * 72];   // 39168 B
    char* yb = (char*)y0s;
    auto yoff = [&](int r, int s, int k) -> int {
        return (((r * 17 + s) * 72 + k) * 2) ^ ((r & 7) << 4);
    };

    short8 xf_[16], wa[16], wb[16];

    {   // x preload (read once, reg-resident)
        const float* xr = xf + (size_t)(r0 + l15) * 4096;
#pragma unroll
        for (int t = 0; t < 8; ++t) {
            const float* p = xr + (wv * 8 + t) * 64 + l4 * 8;
            floatx4 u0 = *reinterpret_cast<const floatx4*>(p);
            floatx4 u1 = *reinterpret_cast<const floatx4*>(p + 4);
            floatx4 u2 = *reinterpret_cast<const floatx4*>(p + 32);
            floatx4 u3 = *reinterpret_cast<const floatx4*>(p + 36);
            short8 a, b;
#pragma unroll
            for (int i = 0; i < 4; ++i) {
                a[i] = (short)f2bf(u0[i]);  a[i + 4] = (short)f2bf(u1[i]);
                b[i] = (short)f2bf(u2[i]);  b[i + 4] = (short)f2bf(u3[i]);
            }
            xf_[t * 2] = a;  xf_[t * 2 + 1] = b;
        }
    }
    auto loadWA = [&](int ss) {
#pragma unroll
        for (int t = 0; t < 8; ++t) {
            const ushort* p =
                wat + ((size_t)(wv * 8 + t) * 128 + ss * 16 + l15) * 64 + l4 * 8;
            wa[t * 2]     = ld8(p);
            wa[t * 2 + 1] = ld8(p + 32);
        }
    };
    auto loadWB = [&](int ss) {
#pragma unroll
        for (int sl = 0; sl < 2; ++sl)
#pragma unroll
            for (int jq = 0; jq < 4; ++jq) {
                const ushort* p =
                    wbt + ((size_t)(ss * 16 + wv * 2 + sl) * 64 + jq * 16 + l15) * 64
                        + l4 * 8;
                wb[(sl * 4 + jq) * 2]     = ld8(p);
                wb[(sl * 4 + jq) * 2 + 1] = ld8(p + 32);
            }
    };

    loadWA(0);

    for (int ss = 0; ss < NS; ++ss) {
        loadWB(ss);

        // stage A: 16 MFMA from registers, packed y0 writes
#pragma unroll
        for (int tp = 0; tp < 4; ++tp) {
            const int t0 = tp * 2, t1 = t0 + 1;
            floatx4 d0 = (floatx4){0.f, 0.f, 0.f, 0.f};
            floatx4 d1 = (floatx4){0.f, 0.f, 0.f, 0.f};
            d0 = MFMA32(xf_[2 * t0],     wa[2 * t0],     d0);
            d0 = MFMA32(xf_[2 * t0 + 1], wa[2 * t0 + 1], d0);
            d1 = MFMA32(xf_[2 * t1],     wa[2 * t1],     d1);
            d1 = MFMA32(xf_[2 * t1 + 1], wa[2 * t1 + 1], d1);
#pragma unroll
            for (int rg = 0; rg < 4; ++rg) {
                uint pk = (uint)f2bf(d0[rg]) | ((uint)f2bf(d1[rg]) << 16);
                *reinterpret_cast<uint*>(
                    yb + yoff(l4 * 4 + rg, l15, wv * 8 + t0)) = pk;
            }
        }
        if (ss + 1 < NS) loadWA(ss + 1);

        lgkm_barrier();           // y0 visible; vmcnt untouched

        floatx4 acc[2][4];
#pragma unroll
        for (int sl = 0; sl < 2; ++sl) {
            const int s_local = wv * 2 + sl;
            short8 af0 = *reinterpret_cast<const short8*>(yb + yoff(l15, s_local, l4 * 8));
            short8 af1 = *reinterpret_cast<const short8*>(yb + yoff(l15, s_local, 32 + l4 * 8));
#pragma unroll
            for (int jq = 0; jq < 4; ++jq) {
                floatx4 t = (floatx4){0.f, 0.f, 0.f, 0.f};
                t = MFMA32(af0, wb[(sl * 4 + jq) * 2],     t);
                t = MFMA32(af1, wb[(sl * 4 + jq) * 2 + 1], t);
                acc[sl][jq] = t;
            }
        }

        lgkm_barrier();           // y0 consumed; y0s reusable as staging

        // epilogue: bias+ELU -> staged (XOR-swz) -> coalesced b128 z-writes
#pragma unroll
        for (int sl = 0; sl < 2; ++sl) {
            const int sg = ss * 16 + wv * 2 + sl;
#pragma unroll
            for (int jq = 0; jq < 4; ++jq) {
                const float bv = bias[sg * 64 + jq * 16 + l15];
                const int col = (wv * 2 + sl) * 64 + jq * 16 + l15;
#pragma unroll
                for (int rg = 0; rg < 4; ++rg) {
                    float v = acc[sl][jq][rg] + bv;
                    v = v > 0.f ? v : (__expf(v) - 1.f);
                    const int row = l4 * 4 + rg;
                    *reinterpret_cast<ushort*>(
                        yb + ((row * 2048 + col * 2) ^ ((row & 7) << 4))) = f2bf(v);
                }
            }
        }
        lgkm_barrier();
#pragma unroll
        for (int p = 0; p < 4; ++p) {
            const int idx = p * 512 + tid;
            const int row = idx >> 7;
            const int c   = idx & 127;
            short8 v = *reinterpret_cast<const short8*>(
                yb + ((row * 2048 + c * 16) ^ ((row & 7) << 4)));
            *reinterpret_cast<short8*>(
                ob + (size_t)(r0 + row) * 8192 + ss * 1024 + c * 8) = v;
        }
        if (ss + 1 < NS) lgkm_barrier();   // staging reads done before next stage A
    }
}

// ---- P3: stage 1_0, block-diag in n. z -> y2t[b][nsl8][j64][nl16] ----
__global__ __launch_bounds__(512, 2) void pass3_k(
    const ushort* __restrict__ z,      // [bs][8192]
    const ushort* __restrict__ w2s,    // [128 n][64 j][64 m] transposed+swz
    ushort* __restrict__ y2t)          // aliases z
{
    const int tid = threadIdx.x, lane = tid & 63, wv = tid >> 6;
    const int l15 = lane & 15, l4 = lane >> 4;
    const int slice = blockIdx.x & 7;              // n-slice 16, XCD-pinned
    const int r0 = (blockIdx.x >> 3) * 128;

    __shared__ __align__(16) ushort wlds[16 * 4096];   // 128 KB
    __shared__ __align__(16) ushort sbuf[16 * 512];    // 16 KB

    {
        const ushort* src = w2s + (size_t)slice * 65536;
        for (int i = 0; i < 16; ++i)
            gload_lds16(src + i * 4096 + tid * 8, &wlds[i * 4096 + tid * 8]);
    }
    __syncthreads();

    short8 wb[2][4][2];
    const char* wp = (const char*)wlds;
#pragma unroll
    for (int nl2 = 0; nl2 < 2; ++nl2)
#pragma unroll
        for (int jq = 0; jq < 4; ++jq)
#pragma unroll
            for (int mh = 0; mh < 2; ++mh) {
                const int byteoff =
                    (((jq * 16 + l15) * 64 + mh * 32 + l4 * 8) * 2) ^ ((l15 & 7) << 4);
                wb[nl2][jq][mh] = *reinterpret_cast<const short8*>(
                    wp + (wv * 2 + nl2) * 8192 + byteoff);
            }

    for (int rt = 0; rt < 8; ++rt) {
        short8 a[2][2];
#pragma unroll
        for (int nl2 = 0; nl2 < 2; ++nl2)
#pragma unroll
            for (int mh = 0; mh < 2; ++mh)
                a[nl2][mh] = ld8(z + (size_t)(r0 + rt * 16 + l15) * 8192
                                   + (slice * 16 + wv * 2 + nl2) * 64 + mh * 32 + l4 * 8);
#pragma unroll
        for (int jh = 0; jh < 2; ++jh) {
#pragma unroll
            for (int jq2 = 0; jq2 < 2; ++jq2) {
                const int jq = jh * 2 + jq2;
                floatx4 d0 = (floatx4){0.f, 0.f, 0.f, 0.f};
                floatx4 d1 = (floatx4){0.f, 0.f, 0.f, 0.f};
                d0 = MFMA32(a[0][0], wb[0][jq][0], d0);
                d0 = MFMA32(a[0][1], wb[0][jq][1], d0);
                d1 = MFMA32(a[1][0], wb[1][jq][0], d1);
                d1 = MFMA32(a[1][1], wb[1][jq][1], d1);
#pragma unroll
                for (int rg = 0; rg < 4; ++rg) {
                    uint pk = (uint)f2bf(d0[rg]) | ((uint)f2bf(d1[rg]) << 16);
                    *reinterpret_cast<uint*>(
                        &sbuf[(l4 * 4 + rg) * 512 + (jq2 * 16 + l15) * 16 + wv * 2]) = pk;
                }
            }
            __syncthreads();
#pragma unroll
            for (int p = 0; p < 2; ++p) {
                const int idx = p * 512 + tid;
                const int row = idx >> 6, c = idx & 63;
                short8 v = *reinterpret_cast<const short8*>(
                    (const char*)sbuf + row * 1024 + c * 16);
                *reinterpret_cast<short8*>(
                    y2t + (size_t)(r0 + rt * 16 + row) * 8192
                        + slice * 1024 + jh * 512 + c * 8) = v;
            }
            __syncthreads();
        }
    }
}

// ---- P4: stage 1_1, block-diag in out-s. y2t -> out f32 (+b3) ----
__global__ __launch_bounds__(512, 2) void pass4_k(
    const ushort* __restrict__ y2t,    // [bs][8][64][16]
    const ushort* __restrict__ w3s,    // [64 s][64 j][128 k] transposed+swz
    const float* __restrict__ b3,      // [4096]
    float* __restrict__ out)           // [bs][4096]
{
    const int tid = threadIdx.x, lane = tid & 63, wv = tid >> 6;
    const int l15 = lane & 15, l4 = lane >> 4;
    const int slice = blockIdx.x & 7;              // 8 s per slice, XCD-pinned
    const int r0 = (blockIdx.x >> 3) * 128;
    const int s = slice * 8 + wv;                  // wave's s-block

    __shared__ __align__(16) ushort wlds[8 * 8192];    // 128 KB
    {
        const ushort* src = w3s + (size_t)slice * 65536;
        for (int i = 0; i < 16; ++i)
            gload_lds16(src + i * 4096 + tid * 8, &wlds[i * 4096 + tid * 8]);
    }
    __syncthreads();

    short8 wb[4][4];
    const char* wp = (const char*)wlds + wv * 16384;
#pragma unroll
    for (int jq = 0; jq < 4; ++jq)
#pragma unroll
        for (int kq = 0; kq < 4; ++kq) {
            const int byteoff =
                (((jq * 16 + l15) * 128 + kq * 32 + l4 * 8) * 2) ^ ((l15 & 7) << 4);
            wb[jq][kq] = *reinterpret_cast<const short8*>(wp + byteoff);
        }

    for (int rt = 0; rt < 8; ++rt) {
        short8 a[4];
#pragma unroll
        for (int kq = 0; kq < 4; ++kq)
            a[kq] = ld8(y2t + (size_t)(r0 + rt * 16 + l15) * 8192
                            + (2 * kq + (l4 >> 1)) * 1024 + s * 16 + (l4 & 1) * 8);
        floatx4 acc[4];
#pragma unroll
        for (int jq = 0; jq < 4; ++jq) acc[jq] = (floatx4){0.f, 0.f, 0.f, 0.f};
#pragma unroll
        for (int kq = 0; kq < 4; ++kq)
#pragma unroll
            for (int jq = 0; jq < 4; ++jq)
                acc[jq] = MFMA32(a[kq], wb[jq][kq], acc[jq]);
#pragma unroll
        for (int jq = 0; jq < 4; ++jq) {
            const float bv = b3[s * 64 + jq * 16 + l15];
#pragma unroll
            for (int rg = 0; rg < 4; ++rg)
                out[(size_t)(r0 + rt * 16 + l4 * 4 + rg) * 4096
                    + s * 64 + jq * 16 + l15] = acc[jq][rg] + bv;
        }
    }
}

extern "C" void kernel_launch(void* const* d_in, const int* in_sizes, int n_in,
                              void* d_out, int out_size, void* d_ws, size_t ws_size,
                              hipStream_t stream) {
    const float* x  = (const float*)d_in[0];
    const float* w0 = (const float*)d_in[1];
    const float* w1 = (const float*)d_in[2];
    const float* b1 = (const float*)d_in[3];
    const float* w2 = (const float*)d_in[4];
    const float* w3 = (const float*)d_in[5];
    const float* b3 = (const float*)d_in[6];
    float* out = (float*)d_out;

    const int bs = in_sizes[0] / 4096;

    // ws (u16): z[bs*8192] | w0t | w1t | w2s | w3s
    ushort* z   = (ushort*)d_ws;
    const size_t zElems = (size_t)bs * 8192;
    ushort* w0t = z + zElems;
    ushort* w1t = w0t + 64 * 128 * 64;
    ushort* w2s = w1t + 128 * 64 * 64;
    ushort* w3s = w2s + 128 * 64 * 64;
    const size_t need = (zElems + 4ull * 524288) * sizeof(ushort);
    if (n_in < 7 || (bs & 127) || ws_size < need) return;

    transpose_cast_k  <<<dim3(512), dim3(256), 0, stream>>>(w0, w0t, 64, 64, 128);
    transpose_cast_k  <<<dim3(512), dim3(256), 0, stream>>>(w1, w1t, 128, 64, 64);
    transpose_cast_swz<<<dim3(512), dim3(256), 0, stream>>>(w2, w2s, 128, 64, 64);
    transpose_cast_swz<<<dim3(512), dim3(256), 0, stream>>>(w3, w3s, 64, 128, 64);

    fusedK1<<<dim3(bs / 16), dim3(512), 0, stream>>>(x, w0t, w1t, b1, z);
    pass3_k<<<dim3((bs / 128) * 8), dim3(512), 0, stream>>>(z, w2s, z /*y2t alias*/);
    pass4_k<<<dim3((bs / 128) * 8), dim3(512), 0, stream>>>(z, w3s, b3, out);
}

// Round 11
// 263.586 us; speedup vs baseline: 1.8058x; 1.2191x over previous
//
#include <hip/hip_runtime.h>

// Monarch block-MLP, round 11: four passes, all in the proven P3/P4 shape
// (weight slice -> LDS once, B-frags -> regs once, main loop = batched
// A-loads + MFMA + LDS-staged coalesced stores).
//   P1 (0_0): x f32 -> y0t[b][sl8][s128][kb8]   (block-diag kb; x read once)
//   P2 (0_1): y0t -> z[b][8192] (+b1, ELU)      (block-diag s; y0t read once)
//   P3 (1_0): z -> y2t[b][nsl8][j64][nl16]      (block-diag n; z read once)
//   P4 (1_1): y2t -> out f32 (+b3)              (block-diag s'; y2t read once)
// y0t aliases d_out (dead until P4 overwrites it); y2t aliases z.

typedef __attribute__((ext_vector_type(8))) short short8;
typedef __attribute__((ext_vector_type(4))) float floatx4;
typedef unsigned int uint;
typedef unsigned short ushort;

#define MFMA32(a, b, c) __builtin_amdgcn_mfma_f32_16x16x32_bf16(a, b, c, 0, 0, 0)

__device__ __forceinline__ ushort f2bf(float f) {
    uint u = __float_as_uint(f);
    uint r = 0x7FFFu + ((u >> 16) & 1u);
    return (ushort)((u + r) >> 16);
}
__device__ __forceinline__ short8 ld8(const ushort* p) {
    return *reinterpret_cast<const short8*>(p);
}
__device__ __forceinline__ void gload_lds16(const void* g, void* l) {
    __builtin_amdgcn_global_load_lds(
        (const __attribute__((address_space(1))) unsigned int*)g,
        (__attribute__((address_space(3))) unsigned int*)l, 16, 0, 0);
}

// Transposed + XOR-swizzled: block b, elem (c,r) at byte ((c*R+r)*2)^((c&7)<<4)
__global__ void transpose_cast_swz(const float* __restrict__ in,
                                   ushort* __restrict__ out,
                                   int Bn, int R, int C) {
    int total = Bn * R * C;
    int stride = gridDim.x * blockDim.x;
    for (int idx = blockIdx.x * blockDim.x + threadIdx.x; idx < total; idx += stride) {
        int rc = R * C;
        int b = idx / rc;
        int rem = idx - b * rc;
        int c = rem / R;
        int r = rem - c * R;
        int byteoff = ((c * R + r) * 2) ^ ((c & 7) << 4);
        *reinterpret_cast<ushort*>((char*)out + (size_t)b * rc * 2 + byteoff) =
            f2bf(in[(size_t)(b * R + r) * C + c]);
    }
}

// MFMA 16x16x32 bf16 layouts (m89-verified):
//   A: row=lane&15, k=(lane>>4)*8+i ; B: col=lane&15, same k
//   D: col=lane&15, row=(lane>>4)*4+reg

// ---- P1: stage 0_0. x (f32) -> y0t[b][sl8][s128][kb8] ----
__global__ __launch_bounds__(512, 2) void pass1_k(
    const float* __restrict__ x,       // [bs][4096]
    const ushort* __restrict__ w0s,    // [64 kb][128 s][64 m] swz
    ushort* __restrict__ y0t)          // [bs][8][128][8]  (= d_out alias)
{
    const int tid = threadIdx.x, lane = tid & 63, wv = tid >> 6;
    const int l15 = lane & 15, l4 = lane >> 4;
    const int slice = blockIdx.x & 7;          // 8 kb per slice, XCD-pinned
    const int r0 = (blockIdx.x >> 3) * 128;
    const int p   = wv & 3;                    // kb pair {2p, 2p+1} in slice
    const int st0 = (wv >> 2) * 4;             // wave's 4 stiles

    __shared__ __align__(16) ushort lds[65536];   // 128 KB: wlds, then sbuf
    {
        const ushort* src = w0s + (size_t)slice * 8 * 8192;
        for (int i = 0; i < 16; ++i)
            gload_lds16(src + i * 4096 + tid * 8, &lds[i * 4096 + tid * 8]);
    }
    __syncthreads();

    short8 wb[2][4][2];                        // [kb-in-pair][stile][mhalf]
    const char* wp = (const char*)lds;
#pragma unroll
    for (int kk = 0; kk < 2; ++kk)
#pragma unroll
        for (int si = 0; si < 4; ++si)
#pragma unroll
            for (int mh = 0; mh < 2; ++mh) {
                const int s = (st0 + si) * 16 + l15;
                const int byteoff = (2 * p + kk) * 16384 +
                    (((s * 64 + mh * 32 + l4 * 8) * 2) ^ ((s & 7) << 4));
                wb[kk][si][mh] = *reinterpret_cast<const short8*>(wp + byteoff);
            }
    __syncthreads();                           // wlds dead -> reuse as sbuf
    char* sb = (char*)lds;

    for (int rt = 0; rt < 8; ++rt) {
        // A: x f32 (full-line coalesced: 4 l4-lanes x 32B = 128B), cvt bf16
        short8 a[2][2];
        const float* xr = x + (size_t)(r0 + rt * 16 + l15) * 4096
                            + (slice * 8 + 2 * p) * 64;
#pragma unroll
        for (int kk = 0; kk < 2; ++kk)
#pragma unroll
            for (int mh = 0; mh < 2; ++mh) {
                const float* q = xr + kk * 64 + mh * 32 + l4 * 8;
                floatx4 u0 = *reinterpret_cast<const floatx4*>(q);
                floatx4 u1 = *reinterpret_cast<const floatx4*>(q + 4);
                short8 v;
#pragma unroll
                for (int i2 = 0; i2 < 4; ++i2) {
                    v[i2]     = (short)f2bf(u0[i2]);
                    v[i2 + 4] = (short)f2bf(u1[i2]);
                }
                a[kk][mh] = v;
            }
#pragma unroll
        for (int si = 0; si < 4; ++si) {
            floatx4 d0 = (floatx4){0.f, 0.f, 0.f, 0.f};
            floatx4 d1 = (floatx4){0.f, 0.f, 0.f, 0.f};
            d0 = MFMA32(a[0][0], wb[0][si][0], d0);
            d0 = MFMA32(a[0][1], wb[0][si][1], d0);
            d1 = MFMA32(a[1][0], wb[1][si][0], d1);
            d1 = MFMA32(a[1][1], wb[1][si][1], d1);
            const int s = (st0 + si) * 16 + l15;
#pragma unroll
            for (int rg = 0; rg < 4; ++rg) {
                const int r = l4 * 4 + rg;
                uint pk = (uint)f2bf(d0[rg]) | ((uint)f2bf(d1[rg]) << 16);
                *reinterpret_cast<uint*>(
                    sb + r * 2048 + ((s * 16 + p * 4) ^ ((r & 7) << 4))) = pk;
            }
        }
        __syncthreads();
        // coalesced chunk write: per row 2KB [s128][kb8] at slice offset
#pragma unroll
        for (int q2 = 0; q2 < 4; ++q2) {
            const int idx = q2 * 512 + tid;
            const int row = idx >> 7, c = idx & 127;
            short8 v = *reinterpret_cast<const short8*>(
                sb + row * 2048 + ((c * 16) ^ ((row & 7) << 4)));
            *reinterpret_cast<short8*>(
                y0t + (size_t)(r0 + rt * 16 + row) * 8192 + slice * 1024 + c * 8) = v;
        }
        __syncthreads();
    }
}

// ---- P2: stage 0_1. y0t -> z (+b1, ELU) ----
__global__ __launch_bounds__(512, 2) void pass2_k(
    const ushort* __restrict__ y0t,    // [bs][8][128][8]
    const ushort* __restrict__ w1s,    // [128 s][64 j][64 kb] swz
    const float* __restrict__ b1,      // [8192]
    ushort* __restrict__ z)            // [bs][8192]
{
    const int tid = threadIdx.x, lane = tid & 63, wv = tid >> 6;
    const int l15 = lane & 15, l4 = lane >> 4;
    const int slice = blockIdx.x & 7;          // 16 s per slice, XCD-pinned
    const int r0 = (blockIdx.x >> 3) * 128;

    __shared__ __align__(16) ushort lds[65536];
    {
        const ushort* src = w1s + (size_t)slice * 16 * 4096;
        for (int i = 0; i < 16; ++i)
            gload_lds16(src + i * 4096 + tid * 8, &lds[i * 4096 + tid * 8]);
    }
    __syncthreads();

    short8 wbf[2][4][2];                       // [s-local][jq][khalf]
    const char* wp = (const char*)lds;
#pragma unroll
    for (int sl = 0; sl < 2; ++sl)
#pragma unroll
        for (int jq = 0; jq < 4; ++jq)
#pragma unroll
            for (int kh = 0; kh < 2; ++kh) {
                const int byteoff = (wv * 2 + sl) * 8192 +
                    ((((jq * 16 + l15) * 64 + kh * 32 + l4 * 8) * 2) ^ ((l15 & 7) << 4));
                wbf[sl][jq][kh] = *reinterpret_cast<const short8*>(wp + byteoff);
            }
    __syncthreads();                           // wlds dead -> sbuf
    char* sb = (char*)lds;
    const float* bp = b1 + (slice * 16 + wv * 2) * 64;

    for (int rt = 0; rt < 8; ++rt) {
        short8 a[2][2];                        // [s-local][khalf]
#pragma unroll
        for (int sl = 0; sl < 2; ++sl)
#pragma unroll
            for (int kh = 0; kh < 2; ++kh)
                a[sl][kh] = ld8(y0t + (size_t)(r0 + rt * 16 + l15) * 8192
                                + (kh * 4 + l4) * 1024
                                + (slice * 16 + wv * 2 + sl) * 8);
#pragma unroll
        for (int sl = 0; sl < 2; ++sl) {
            const int s_l = wv * 2 + sl;
#pragma unroll
            for (int jq = 0; jq < 4; ++jq) {
                floatx4 t = (floatx4){0.f, 0.f, 0.f, 0.f};
                t = MFMA32(a[sl][0], wbf[sl][jq][0], t);
                t = MFMA32(a[sl][1], wbf[sl][jq][1], t);
                const float bv = bp[sl * 64 + jq * 16 + l15];
#pragma unroll
                for (int rg = 0; rg < 4; ++rg) {
                    float v = t[rg] + bv;
                    v = v > 0.f ? v : (__expf(v) - 1.f);
                    const int r = l4 * 4 + rg;
                    *reinterpret_cast<ushort*>(
                        sb + r * 2048 +
                        ((s_l * 128 + jq * 32 + l15 * 2) ^ ((r & 7) << 4))) = f2bf(v);
                }
            }
        }
        __syncthreads();
#pragma unroll
        for (int q2 = 0; q2 < 4; ++q2) {
            const int idx = q2 * 512 + tid;
            const int row = idx >> 7, c = idx & 127;
            short8 v = *reinterpret_cast<const short8*>(
                sb + row * 2048 + ((c * 16) ^ ((row & 7) << 4)));
            *reinterpret_cast<short8*>(
                z + (size_t)(r0 + rt * 16 + row) * 8192 + slice * 1024 + c * 8) = v;
        }
        __syncthreads();
    }
}

// ---- P3: stage 1_0, block-diag in n. z -> y2t[b][nsl8][j64][nl16] ----
__global__ __launch_bounds__(512, 2) void pass3_k(
    const ushort* __restrict__ z,      // [bs][8192]
    const ushort* __restrict__ w2s,    // [128 n][64 j][64 m] transposed+swz
    ushort* __restrict__ y2t)          // aliases z
{
    const int tid = threadIdx.x, lane = tid & 63, wv = tid >> 6;
    const int l15 = lane & 15, l4 = lane >> 4;
    const int slice = blockIdx.x & 7;
    const int r0 = (blockIdx.x >> 3) * 128;

    __shared__ __align__(16) ushort wlds[16 * 4096];   // 128 KB
    __shared__ __align__(16) ushort sbuf[16 * 512];    // 16 KB
    {
        const ushort* src = w2s + (size_t)slice * 65536;
        for (int i = 0; i < 16; ++i)
            gload_lds16(src + i * 4096 + tid * 8, &wlds[i * 4096 + tid * 8]);
    }
    __syncthreads();

    short8 wb[2][4][2];
    const char* wp = (const char*)wlds;
#pragma unroll
    for (int nl2 = 0; nl2 < 2; ++nl2)
#pragma unroll
        for (int jq = 0; jq < 4; ++jq)
#pragma unroll
            for (int mh = 0; mh < 2; ++mh) {
                const int byteoff =
                    (((jq * 16 + l15) * 64 + mh * 32 + l4 * 8) * 2) ^ ((l15 & 7) << 4);
                wb[nl2][jq][mh] = *reinterpret_cast<const short8*>(
                    wp + (wv * 2 + nl2) * 8192 + byteoff);
            }

    for (int rt = 0; rt < 8; ++rt) {
        short8 a[2][2];
#pragma unroll
        for (int nl2 = 0; nl2 < 2; ++nl2)
#pragma unroll
            for (int mh = 0; mh < 2; ++mh)
                a[nl2][mh] = ld8(z + (size_t)(r0 + rt * 16 + l15) * 8192
                                   + (slice * 16 + wv * 2 + nl2) * 64 + mh * 32 + l4 * 8);
#pragma unroll
        for (int jh = 0; jh < 2; ++jh) {
#pragma unroll
            for (int jq2 = 0; jq2 < 2; ++jq2) {
                const int jq = jh * 2 + jq2;
                floatx4 d0 = (floatx4){0.f, 0.f, 0.f, 0.f};
                floatx4 d1 = (floatx4){0.f, 0.f, 0.f, 0.f};
                d0 = MFMA32(a[0][0], wb[0][jq][0], d0);
                d0 = MFMA32(a[0][1], wb[0][jq][1], d0);
                d1 = MFMA32(a[1][0], wb[1][jq][0], d1);
                d1 = MFMA32(a[1][1], wb[1][jq][1], d1);
#pragma unroll
                for (int rg = 0; rg < 4; ++rg) {
                    uint pk = (uint)f2bf(d0[rg]) | ((uint)f2bf(d1[rg]) << 16);
                    *reinterpret_cast<uint*>(
                        &sbuf[(l4 * 4 + rg) * 512 + (jq2 * 16 + l15) * 16 + wv * 2]) = pk;
                }
            }
            __syncthreads();
#pragma unroll
            for (int p = 0; p < 2; ++p) {
                const int idx = p * 512 + tid;
                const int row = idx >> 6, c = idx & 63;
                short8 v = *reinterpret_cast<const short8*>(
                    (const char*)sbuf + row * 1024 + c * 16);
                *reinterpret_cast<short8*>(
                    y2t + (size_t)(r0 + rt * 16 + row) * 8192
                        + slice * 1024 + jh * 512 + c * 8) = v;
            }
            __syncthreads();
        }
    }
}

// ---- P4: stage 1_1, block-diag in out-s. y2t -> out f32 (+b3) ----
__global__ __launch_bounds__(512, 2) void pass4_k(
    const ushort* __restrict__ y2t,    // [bs][8][64][16]
    const ushort* __restrict__ w3s,    // [64 s][64 j][128 k] transposed+swz
    const float* __restrict__ b3,      // [4096]
    float* __restrict__ out)           // [bs][4096]
{
    const int tid = threadIdx.x, lane = tid & 63, wv = tid >> 6;
    const int l15 = lane & 15, l4 = lane >> 4;
    const int slice = blockIdx.x & 7;
    const int r0 = (blockIdx.x >> 3) * 128;
    const int s = slice * 8 + wv;

    __shared__ __align__(16) ushort wlds[8 * 8192];    // 128 KB
    {
        const ushort* src = w3s + (size_t)slice * 65536;
        for (int i = 0; i < 16; ++i)
            gload_lds16(src + i * 4096 + tid * 8, &wlds[i * 4096 + tid * 8]);
    }
    __syncthreads();

    short8 wb[4][4];
    const char* wp = (const char*)wlds + wv * 16384;
#pragma unroll
    for (int jq = 0; jq < 4; ++jq)
#pragma unroll
        for (int kq = 0; kq < 4; ++kq) {
            const int byteoff =
                (((jq * 16 + l15) * 128 + kq * 32 + l4 * 8) * 2) ^ ((l15 & 7) << 4);
            wb[jq][kq] = *reinterpret_cast<const short8*>(wp + byteoff);
        }

    for (int rt = 0; rt < 8; ++rt) {
        short8 a[4];
#pragma unroll
        for (int kq = 0; kq < 4; ++kq)
            a[kq] = ld8(y2t + (size_t)(r0 + rt * 16 + l15) * 8192
                            + (2 * kq + (l4 >> 1)) * 1024 + s * 16 + (l4 & 1) * 8);
        floatx4 acc[4];
#pragma unroll
        for (int jq = 0; jq < 4; ++jq) acc[jq] = (floatx4){0.f, 0.f, 0.f, 0.f};
#pragma unroll
        for (int kq = 0; kq < 4; ++kq)
#pragma unroll
            for (int jq = 0; jq < 4; ++jq)
                acc[jq] = MFMA32(a[kq], wb[jq][kq], acc[jq]);
#pragma unroll
        for (int jq = 0; jq < 4; ++jq) {
            const float bv = b3[s * 64 + jq * 16 + l15];
#pragma unroll
            for (int rg = 0; rg < 4; ++rg)
                out[(size_t)(r0 + rt * 16 + l4 * 4 + rg) * 4096
                    + s * 64 + jq * 16 + l15] = acc[jq][rg] + bv;
        }
    }
}

extern "C" void kernel_launch(void* const* d_in, const int* in_sizes, int n_in,
                              void* d_out, int out_size, void* d_ws, size_t ws_size,
                              hipStream_t stream) {
    const float* x  = (const float*)d_in[0];
    const float* w0 = (const float*)d_in[1];
    const float* w1 = (const float*)d_in[2];
    const float* b1 = (const float*)d_in[3];
    const float* w2 = (const float*)d_in[4];
    const float* w3 = (const float*)d_in[5];
    const float* b3 = (const float*)d_in[6];
    float* out = (float*)d_out;

    const int bs = in_sizes[0] / 4096;

    // ws (u16): z[bs*8192] | w0s | w1s | w2s | w3s   (y0t lives in d_out)
    ushort* z   = (ushort*)d_ws;
    const size_t zElems = (size_t)bs * 8192;
    ushort* w0s = z + zElems;
    ushort* w1s = w0s + 64 * 128 * 64;
    ushort* w2s = w1s + 128 * 64 * 64;
    ushort* w3s = w2s + 128 * 64 * 64;
    const size_t need = (zElems + 4ull * 524288) * sizeof(ushort);
    if (n_in < 7 || (bs & 127) || ws_size < need) return;

    ushort* y0t = (ushort*)d_out;      // dead until P4 overwrites it

    transpose_cast_swz<<<dim3(512), dim3(256), 0, stream>>>(w0, w0s, 64, 64, 128);
    transpose_cast_swz<<<dim3(512), dim3(256), 0, stream>>>(w1, w1s, 128, 64, 64);
    transpose_cast_swz<<<dim3(512), dim3(256), 0, stream>>>(w2, w2s, 128, 64, 64);
    transpose_cast_swz<<<dim3(512), dim3(256), 0, stream>>>(w3, w3s, 64, 128, 64);

    pass1_k<<<dim3((bs / 128) * 8), dim3(512), 0, stream>>>(x, w0s, y0t);
    pass2_k<<<dim3((bs / 128) * 8), dim3(512), 0, stream>>>(y0t, w1s, b1, z);
    pass3_k<<<dim3((bs / 128) * 8), dim3(512), 0, stream>>>(z, w2s, z /*y2t alias*/);
    pass4_k<<<dim3((bs / 128) * 8), dim3(512), 0, stream>>>(z, w3s, b3, out);
}